// Round 9
// baseline (1197.413 us; speedup 1.0000x reference)
//
#include <hip/hip_runtime.h>
#include <hip/hip_bf16.h>
#include <hip/hip_cooperative_groups.h>

namespace cg = cooperative_groups;

#define NN 8192
#define NE 262144
#define CAP 96
#define AWK 136   // 128 + 8 pad (ushorts)

typedef __attribute__((ext_vector_type(8))) __bf16 bf16x8;
typedef __attribute__((ext_vector_type(4))) float f32x4;

__device__ __forceinline__ ushort f2b(float v) {
    __hip_bfloat16 b = __float2bfloat16(v);
    return *reinterpret_cast<ushort*>(&b);
}
__device__ __forceinline__ uint pack2(float lo, float hi) {
    return (uint)f2b(lo) | ((uint)f2b(hi) << 16);
}
__device__ __forceinline__ float b2f(ushort u) {
    return __uint_as_float(((uint)u) << 16);
}

struct MegaArgs {
    const int* src; const int* dst; const float* ew;
    int* cnt; uint2* slots;
    const float* feat;
    const float* w[9]; ushort* wt[9];
    const float* bp1; const float* b1;
    const float* bp2; const float* b2;
    const float* bp3; const float* b3;
    ushort* P; ushort* G; ushort* X; ushort* Y; ushort* Cs; ushort* hdb;
    float* out;
};

// ---------------------------------------------------------------------------
// 64x64 GEMM tile, BK=128: C[by,bx] = act(A @ BT^T + addend)
// A [8192][K] (f32 on-the-fly convert if A1F32, else bf16), BT [N][K] bf16.
// 4 waves (2x2), wave tile 32x32. OUTMODE: 0=bf16, 1=f32, 2=both.
// ADDC: addend = bf16 cin[row][col]; else bias[col].
// ---------------------------------------------------------------------------
template <bool A1F32, bool RELU, int OUTMODE, bool ADDC>
__device__ __forceinline__ void gemm_tile64(
    int by, int bx, const void* __restrict__ Av, const ushort* __restrict__ BT,
    int K, const float* __restrict__ bias, const ushort* __restrict__ cin,
    float* __restrict__ Cf, ushort* __restrict__ Cb, int N,
    ushort* As, ushort* Bs) {
    const int tid = threadIdx.x, lane = tid & 63, wave = tid >> 6;
    const int wm = (wave >> 1) * 32, wn = (wave & 1) * 32;
    const int r16 = lane & 15, kb = lane >> 4;
    const int m0 = by * 64, n0 = bx * 64;

    f32x4 acc[2][2];
#pragma unroll
    for (int i = 0; i < 2; ++i)
#pragma unroll
        for (int j = 0; j < 2; ++j) acc[i][j] = (f32x4)(0.f);

    for (int k0 = 0; k0 < K; k0 += 128) {
        if constexpr (A1F32) {
            const float* A = (const float*)Av;
#pragma unroll
            for (int rep = 0; rep < 8; ++rep) {
                int id = rep * 256 + tid;
                int row = id >> 5, c = id & 31;
                float4 f = *(const float4*)&A[(size_t)(m0 + row) * K + k0 + c * 4];
                uint2 o; o.x = pack2(f.x, f.y); o.y = pack2(f.z, f.w);
                *(uint2*)&As[row * AWK + c * 4] = o;
            }
        } else {
            const ushort* A = (const ushort*)Av;
#pragma unroll
            for (int rep = 0; rep < 4; ++rep) {
                int id = rep * 256 + tid;
                int row = id >> 4, c = id & 15;
                *(bf16x8*)&As[row * AWK + c * 8] =
                    *(const bf16x8*)&A[(size_t)(m0 + row) * K + k0 + c * 8];
            }
        }
#pragma unroll
        for (int rep = 0; rep < 4; ++rep) {
            int id = rep * 256 + tid;
            int row = id >> 4, c = id & 15;
            *(bf16x8*)&Bs[row * AWK + c * 8] =
                *(const bf16x8*)&BT[(size_t)(n0 + row) * K + k0 + c * 8];
        }
        __syncthreads();
#pragma unroll
        for (int kc = 0; kc < 4; ++kc) {
            bf16x8 a[2], b[2];
#pragma unroll
            for (int i = 0; i < 2; ++i)
                a[i] = *(const bf16x8*)&As[(wm + 16 * i + r16) * AWK + kc * 32 + kb * 8];
#pragma unroll
            for (int j = 0; j < 2; ++j)
                b[j] = *(const bf16x8*)&Bs[(wn + 16 * j + r16) * AWK + kc * 32 + kb * 8];
#pragma unroll
            for (int i = 0; i < 2; ++i)
#pragma unroll
                for (int j = 0; j < 2; ++j)
                    acc[i][j] = __builtin_amdgcn_mfma_f32_16x16x32_bf16(a[i], b[j], acc[i][j], 0, 0, 0);
        }
        __syncthreads();
    }

#pragma unroll
    for (int i = 0; i < 2; ++i) {
#pragma unroll
        for (int j = 0; j < 2; ++j) {
            int col = n0 + wn + 16 * j + r16;
            float bv = ADDC ? 0.f : bias[col];
#pragma unroll
            for (int r = 0; r < 4; ++r) {
                int row = m0 + wm + 16 * i + kb * 4 + r;
                float v = acc[i][j][r];
                if constexpr (ADDC) v += b2f(cin[(size_t)row * N + col]);
                else v += bv;
                if (RELU) v = fmaxf(v, 0.f);
                if (OUTMODE != 0) Cf[(size_t)row * N + col] = v;
                if (OUTMODE != 1) Cb[(size_t)row * N + col] = f2b(v);
            }
        }
    }
}

// ---------------------------------------------------------------------------
// segmax for 4 nodes (1 wave each): G[node] = max over slots (0 if none)
// ---------------------------------------------------------------------------
template <int DIN>
__device__ __forceinline__ void seg4(
    int grp, const ushort* __restrict__ Pin, const int* __restrict__ cnt,
    const uint2* __restrict__ slots, ushort* __restrict__ G) {
    constexpr int FPL = DIN / 64;
    const int lane = threadIdx.x & 63, wave = threadIdx.x >> 6;
    int node = grp * 4 + wave;
    int f0 = lane * FPL;
    int n = cnt[node]; if (n > CAP) n = CAP;
    const uint2* sl = &slots[(size_t)node * CAP];
    float mx[FPL];
#pragma unroll
    for (int i = 0; i < FPL; ++i) mx[i] = 0.f;
    auto upd = [&](uint s, float w) {
        const uint* hp = (const uint*)&Pin[(size_t)s * DIN + f0];
#pragma unroll
        for (int c = 0; c < FPL / 2; ++c) {
            uint u = hp[c];
            float lo = __uint_as_float(u << 16);
            float hi = __uint_as_float(u & 0xffff0000u);
            mx[2 * c] = fmaxf(mx[2 * c], lo * w);
            mx[2 * c + 1] = fmaxf(mx[2 * c + 1], hi * w);
        }
    };
    int e = 0;
    for (; e + 8 <= n; e += 8) {
        uint2 d[8];
#pragma unroll
        for (int t = 0; t < 8; ++t) d[t] = sl[e + t];
#pragma unroll
        for (int t = 0; t < 8; ++t) upd(d[t].x, __uint_as_float(d[t].y));
    }
    for (; e < n; ++e) { uint2 d = sl[e]; upd(d.x, __uint_as_float(d.y)); }
    uint* gp = (uint*)&G[(size_t)node * DIN + f0];
#pragma unroll
    for (int c = 0; c < FPL / 2; ++c) gp[c] = pack2(mx[2 * c], mx[2 * c + 1]);
}

// ---------------------------------------------------------------------------
// phases (grid-stride over items; every thread reaches the end)
// ---------------------------------------------------------------------------
template <int PH>
__device__ void run_phase(const MegaArgs& a, ushort* As, ushort* Bs) {
    const int tid = threadIdx.x;
    const int GRID = (int)gridDim.x;
    if constexpr (PH == 0) {        // zero cnt + weight transposes
        for (int it = blockIdx.x; it < 32 + 1472; it += GRID) {
            if (it < 32) { a.cnt[it * 256 + tid] = 0; continue; }
            int id = (it - 32) * 256 + tid;
            if (id >= 376832) continue;
            const int cum[10] = {0, 16384, 49152, 81920, 147456, 212992, 278528, 344064, 360448, 376832};
            const int KK[9] = {128, 128, 128, 256, 256, 256, 256, 256, 256};
            const int LN[9] = {7, 8, 8, 8, 8, 8, 8, 6, 6};
            int m = 0;
#pragma unroll
            for (int t = 1; t < 9; ++t) m += (id >= cum[t]);
            int local = id - cum[m];
            int K = KK[m], ln = LN[m];
            int k = local >> ln, n = local & ((1 << ln) - 1);
            a.wt[m][n * K + k] = f2b(a.w[m][local]);
        }
    } else if constexpr (PH == 1) { // pool1 (256 tiles) || scatter (1024 chunks)
        for (int it = blockIdx.x; it < 256 + 1024; it += GRID) {
            if (it < 256) {
                gemm_tile64<true, true, 0, false>(it >> 1, it & 1, a.feat, a.wt[0], 128,
                                                  a.bp1, nullptr, nullptr, a.P, 128, As, Bs);
            } else {
                int e = (it - 256) * 256 + tid;
                int d = a.dst[e];
                int p = atomicAdd(&a.cnt[d], 1);
                if (p < CAP) a.slots[(size_t)d * CAP + p] =
                    make_uint2((uint)a.src[e], __float_as_uint(a.ew[e]));
            }
        }
    } else if constexpr (PH == 2) { // self1 (512) || seg1 (2048)
        for (int it = blockIdx.x; it < 512 + 2048; it += GRID) {
            if (it < 512)
                gemm_tile64<true, false, 0, false>(it >> 2, it & 3, a.feat, a.wt[1], 128,
                                                   a.b1, nullptr, nullptr, a.Cs, 256, As, Bs);
            else
                seg4<128>(it - 512, a.P, a.cnt, a.slots, a.G);
        }
    } else if constexpr (PH == 3) { // neigh1 -> X (512)
        for (int it = blockIdx.x; it < 512; it += GRID)
            gemm_tile64<false, true, 0, true>(it >> 2, it & 3, a.G, a.wt[2], 128,
                                              nullptr, a.Cs, nullptr, a.X, 256, As, Bs);
    } else if constexpr (PH == 4) { // pool2 (512) || self2 (512)
        for (int it = blockIdx.x; it < 1024; it += GRID) {
            if (it < 512)
                gemm_tile64<false, true, 0, false>(it >> 2, it & 3, a.X, a.wt[3], 256,
                                                   a.bp2, nullptr, nullptr, a.P, 256, As, Bs);
            else {
                int t2 = it - 512;
                gemm_tile64<false, false, 0, false>(t2 >> 2, t2 & 3, a.X, a.wt[4], 256,
                                                    a.b2, nullptr, nullptr, a.Cs, 256, As, Bs);
            }
        }
    } else if constexpr (PH == 5) { // seg2 (2048)
        for (int it = blockIdx.x; it < 2048; it += GRID)
            seg4<256>(it, a.P, a.cnt, a.slots, a.G);
    } else if constexpr (PH == 6) { // neigh2 -> Y (512)
        for (int it = blockIdx.x; it < 512; it += GRID)
            gemm_tile64<false, true, 0, true>(it >> 2, it & 3, a.G, a.wt[5], 256,
                                              nullptr, a.Cs, nullptr, a.Y, 256, As, Bs);
    } else if constexpr (PH == 7) { // pool3 (512) || self3 (128)
        for (int it = blockIdx.x; it < 640; it += GRID) {
            if (it < 512)
                gemm_tile64<false, true, 0, false>(it >> 2, it & 3, a.Y, a.wt[6], 256,
                                                   a.bp3, nullptr, nullptr, a.P, 256, As, Bs);
            else
                gemm_tile64<false, false, 0, false>(it - 512, 0, a.Y, a.wt[7], 256,
                                                    a.b3, nullptr, nullptr, a.Cs, 64, As, Bs);
        }
    } else if constexpr (PH == 8) { // seg3 (2048)
        for (int it = blockIdx.x; it < 2048; it += GRID)
            seg4<256>(it, a.P, a.cnt, a.slots, a.G);
    } else if constexpr (PH == 9) { // neigh3 -> hd (128)
        for (int it = blockIdx.x; it < 128; it += GRID)
            gemm_tile64<false, true, 2, true>(it, 0, a.G, a.wt[8], 256,
                                              nullptr, a.Cs, a.out, a.hdb, 64, As, Bs);
    }
}

__global__ __launch_bounds__(256, 4) void mega_k(MegaArgs a) {
    __shared__ __align__(16) ushort As[64 * AWK];
    __shared__ __align__(16) ushort Bs[64 * AWK];
    cg::grid_group g = cg::this_grid();
    run_phase<0>(a, As, Bs); g.sync();
    run_phase<1>(a, As, Bs); g.sync();
    run_phase<2>(a, As, Bs); g.sync();
    run_phase<3>(a, As, Bs); g.sync();
    run_phase<4>(a, As, Bs); g.sync();
    run_phase<5>(a, As, Bs); g.sync();
    run_phase<6>(a, As, Bs); g.sync();
    run_phase<7>(a, As, Bs); g.sync();
    run_phase<8>(a, As, Bs); g.sync();
    run_phase<9>(a, As, Bs);
}

template <int PH>
__global__ __launch_bounds__(256, 4) void phase_k(MegaArgs a) {
    __shared__ __align__(16) ushort As[64 * AWK];
    __shared__ __align__(16) ushort Bs[64 * AWK];
    run_phase<PH>(a, As, Bs);
}

// ---------------------------------------------------------------------------
// adj = H @ H^T, H [8192][64] bf16, C fp32. 128x128 tile, K=64 single stage.
// ---------------------------------------------------------------------------
__global__ __launch_bounds__(256) void aat_k(const ushort* __restrict__ H,
                                             float* __restrict__ C) {
    __shared__ __align__(16) ushort As[128 * 72];
    __shared__ __align__(16) ushort Bs[128 * 72];
    int tid = threadIdx.x, lane = tid & 63, wave = tid >> 6;
    int wm = (wave >> 1) * 64, wn = (wave & 1) * 64;
    int r16 = lane & 15, kb = lane >> 4;
    int m0 = blockIdx.y * 128, n0 = blockIdx.x * 128;

#pragma unroll
    for (int rep = 0; rep < 4; ++rep) {
        int id = rep * 256 + tid;
        int row = id >> 3, c = id & 7;
        *(bf16x8*)&As[row * 72 + c * 8] = *(const bf16x8*)&H[(size_t)(m0 + row) * 64 + c * 8];
        *(bf16x8*)&Bs[row * 72 + c * 8] = *(const bf16x8*)&H[(size_t)(n0 + row) * 64 + c * 8];
    }
    __syncthreads();

    f32x4 acc[4][4];
#pragma unroll
    for (int i = 0; i < 4; ++i)
#pragma unroll
        for (int j = 0; j < 4; ++j) acc[i][j] = (f32x4)(0.f);

#pragma unroll
    for (int kc = 0; kc < 2; ++kc) {
        bf16x8 a[4], b[4];
#pragma unroll
        for (int i = 0; i < 4; ++i)
            a[i] = *(const bf16x8*)&As[(wm + 16 * i + r16) * 72 + kc * 32 + kb * 8];
#pragma unroll
        for (int j = 0; j < 4; ++j)
            b[j] = *(const bf16x8*)&Bs[(wn + 16 * j + r16) * 72 + kc * 32 + kb * 8];
#pragma unroll
        for (int i = 0; i < 4; ++i)
#pragma unroll
            for (int j = 0; j < 4; ++j)
                acc[i][j] = __builtin_amdgcn_mfma_f32_16x16x32_bf16(a[i], b[j], acc[i][j], 0, 0, 0);
    }

#pragma unroll
    for (int i = 0; i < 4; ++i) {
#pragma unroll
        for (int j = 0; j < 4; ++j) {
            int col = n0 + wn + 16 * j + r16;
#pragma unroll
            for (int r = 0; r < 4; ++r) {
                size_t row = m0 + wm + 16 * i + kb * 4 + r;
                C[row * NN + col] = acc[i][j][r];
            }
        }
    }
}

// ---------------------------------------------------------------------------
extern "C" void kernel_launch(void* const* d_in, const int* in_sizes, int n_in,
                              void* d_out, int out_size, void* d_ws, size_t ws_size,
                              hipStream_t stream) {
    const float* feat = (const float*)d_in[0];
    const int* src = (const int*)d_in[1];
    const int* dst = (const int*)d_in[2];
    const float* ew = (const float*)d_in[3];
    const float* Wp1 = (const float*)d_in[5];
    const float* bp1 = (const float*)d_in[6];
    const float* Ws1 = (const float*)d_in[7];
    const float* Wn1 = (const float*)d_in[8];
    const float* b1  = (const float*)d_in[9];
    const float* Wp2 = (const float*)d_in[10];
    const float* bp2 = (const float*)d_in[11];
    const float* Ws2 = (const float*)d_in[12];
    const float* Wn2 = (const float*)d_in[13];
    const float* b2  = (const float*)d_in[14];
    const float* Wp3 = (const float*)d_in[15];
    const float* bp3 = (const float*)d_in[16];
    const float* Ws3 = (const float*)d_in[17];
    const float* Wn3 = (const float*)d_in[18];
    const float* b3  = (const float*)d_in[19];

    float* out = (float*)d_out;          // hd fp32 [8192][64]
    float* adj = out + (size_t)NN * 64;  // adj fp32 [8192][8192]

    char* ws = (char*)d_ws;
    MegaArgs a;
    a.src = src; a.dst = dst; a.ew = ew;
    a.cnt   = (int*)(ws + 0x0);
    a.slots = (uint2*)(ws + 0x10000);
    a.feat = feat;
    const float* wsrc[9] = {Wp1, Ws1, Wn1, Wp2, Ws2, Wn2, Wp3, Ws3, Wn3};
    ushort* wdst[9] = {
        (ushort*)(ws + 0x620000), (ushort*)(ws + 0x628000), (ushort*)(ws + 0x638000),
        (ushort*)(ws + 0x648000), (ushort*)(ws + 0x668000), (ushort*)(ws + 0x688000),
        (ushort*)(ws + 0x6A8000), (ushort*)(ws + 0x6C8000), (ushort*)(ws + 0x6D0000)};
    for (int i = 0; i < 9; ++i) { a.w[i] = wsrc[i]; a.wt[i] = wdst[i]; }
    a.bp1 = bp1; a.b1 = b1; a.bp2 = bp2; a.b2 = b2; a.bp3 = bp3; a.b3 = b3;
    a.P  = (ushort*)(ws + 0x700000);
    a.G  = (ushort*)(ws + 0xB00000);
    a.X  = (ushort*)(ws + 0xF00000);
    a.Y  = (ushort*)(ws + 0x1300000);
    a.Cs = (ushort*)(ws + 0x1700000);
    a.hdb = (ushort*)(ws + 0x1B00000);
    a.out = out;

    void* kargs[] = {(void*)&a};
    hipError_t ce = hipLaunchCooperativeKernel((const void*)mega_k, dim3(1024), dim3(256),
                                               kargs, 0, stream);
    if (ce != hipSuccess) {
        // deterministic fallback: same phases as ordinary kernels
        phase_k<0><<<1024, 256, 0, stream>>>(a);
        phase_k<1><<<1024, 256, 0, stream>>>(a);
        phase_k<2><<<1024, 256, 0, stream>>>(a);
        phase_k<3><<<1024, 256, 0, stream>>>(a);
        phase_k<4><<<1024, 256, 0, stream>>>(a);
        phase_k<5><<<1024, 256, 0, stream>>>(a);
        phase_k<6><<<1024, 256, 0, stream>>>(a);
        phase_k<7><<<1024, 256, 0, stream>>>(a);
        phase_k<8><<<1024, 256, 0, stream>>>(a);
        phase_k<9><<<1024, 256, 0, stream>>>(a);
    }

    // adj = hd @ hd^T
    aat_k<<<dim3(NN / 128, NN / 128), 256, 0, stream>>>(a.hdb, adj);
}

// Round 10
// 187.124 us; speedup vs baseline: 6.3990x; 6.3990x over previous
//
#include <hip/hip_runtime.h>
#include <hip/hip_bf16.h>

#define NN 8192
#define NE 262144
#define CAP 96
#define AWK 136   // 128 + 8 pad (ushorts)

typedef __attribute__((ext_vector_type(8))) __bf16 bf16x8;
typedef __attribute__((ext_vector_type(4))) float f32x4;

__device__ __forceinline__ ushort f2b(float v) {
    __hip_bfloat16 b = __float2bfloat16(v);
    return *reinterpret_cast<ushort*>(&b);
}
__device__ __forceinline__ uint pack2(float lo, float hi) {
    return (uint)f2b(lo) | ((uint)f2b(hi) << 16);
}
__device__ __forceinline__ float b2f(ushort u) {
    return __uint_as_float(((uint)u) << 16);
}

// ---------------------------------------------------------------------------
// prep+scatter: blocks 0..1023 scatter edges; 1024..2495 weight transposes
// ([K][N] f32 -> [N][K] bf16, into concatenated [Wp|Ws] buffers); 2496: biases.
// cnt zeroed by memset before this kernel.
// ---------------------------------------------------------------------------
struct PrepArgs {
    const int* src; const int* dst; const float* ew;
    int* cnt; uint2* slots;
    const float* w[9]; ushort* wt[9];
    const float* bp1; const float* b1; const float* bp2; const float* b2;
    const float* bp3; const float* b3;
    float* bcat1; float* bcat2; float* bcat3;
};

__global__ __launch_bounds__(256) void prep_scatter_k(PrepArgs a) {
    const int bid = blockIdx.x, tid = threadIdx.x;
    if (bid < 1024) {
        int e = bid * 256 + tid;
        int d = a.dst[e];
        int p = atomicAdd(&a.cnt[d], 1);
        if (p < CAP) a.slots[(size_t)d * CAP + p] = make_uint2((uint)a.src[e], __float_as_uint(a.ew[e]));
        return;
    }
    if (bid == 2496) {                    // bias concats
        for (int i = tid; i < 128; i += 256) a.bcat1[i] = a.bp1[i];
        for (int i = tid; i < 256; i += 256) {
            a.bcat1[128 + i] = a.b1[i];
            a.bcat2[i] = a.bp2[i];
            a.bcat2[256 + i] = a.b2[i];
            a.bcat3[i] = a.bp3[i];
        }
        for (int i = tid; i < 64; i += 256) a.bcat3[256 + i] = a.b3[i];
        return;
    }
    int id = (bid - 1024) * 256 + tid;    // weight transpose, 376832 total
    if (id >= 376832) return;
    const int cum[10] = {0, 16384, 49152, 81920, 147456, 212992, 278528, 344064, 360448, 376832};
    const int KK[9] = {128, 128, 128, 256, 256, 256, 256, 256, 256};
    const int LN[9] = {7, 8, 8, 8, 8, 8, 8, 6, 6};   // log2(N)
    int m = 0;
#pragma unroll
    for (int t = 1; t < 9; ++t) m += (id >= cum[t]);
    int local = id - cum[m];
    int K = KK[m], ln = LN[m];
    int k = local >> ln, n = local & ((1 << ln) - 1);
    a.wt[m][n * K + k] = f2b(a.w[m][local]);
}

// ---------------------------------------------------------------------------
// pool+self fused GEMM, BK=128, 64x64 tiles: over concatenated N = NP + NS.
// cols [0,NP)   -> P  = relu(A @ Wp^T + bp)  (bf16)
// cols [NP,..)  -> Cs =      A @ Ws^T + b    (bf16)
// A [8192][K]: f32 converted on the fly if A1F32, else bf16.
// ---------------------------------------------------------------------------
template <int NP, int NS, bool A1F32>
__global__ __launch_bounds__(256, 4) void ps_gemm_k(
    const void* __restrict__ Av, const ushort* __restrict__ WT, int K,
    const float* __restrict__ bcat, ushort* __restrict__ P, ushort* __restrict__ Cs) {
    __shared__ __align__(16) ushort As[64 * AWK];
    __shared__ __align__(16) ushort Bs[64 * AWK];

    const int tid = threadIdx.x, lane = tid & 63, wave = tid >> 6;
    const int wm = (wave >> 1) * 32, wn = (wave & 1) * 32;
    const int r16 = lane & 15, kb = lane >> 4;
    const int m0 = blockIdx.y * 64, n0 = blockIdx.x * 64;

    f32x4 acc[2][2];
#pragma unroll
    for (int i = 0; i < 2; ++i)
#pragma unroll
        for (int j = 0; j < 2; ++j) acc[i][j] = (f32x4)(0.f);

    for (int k0 = 0; k0 < K; k0 += 128) {
        if constexpr (A1F32) {
            const float* A = (const float*)Av;
#pragma unroll
            for (int rep = 0; rep < 8; ++rep) {
                int id = rep * 256 + tid;
                int row = id >> 5, c = id & 31;
                float4 f = *(const float4*)&A[(size_t)(m0 + row) * K + k0 + c * 4];
                uint2 o; o.x = pack2(f.x, f.y); o.y = pack2(f.z, f.w);
                *(uint2*)&As[row * AWK + c * 4] = o;
            }
        } else {
            const ushort* A = (const ushort*)Av;
#pragma unroll
            for (int rep = 0; rep < 4; ++rep) {
                int id = rep * 256 + tid;
                int row = id >> 4, c = id & 15;
                *(bf16x8*)&As[row * AWK + c * 8] =
                    *(const bf16x8*)&A[(size_t)(m0 + row) * K + k0 + c * 8];
            }
        }
#pragma unroll
        for (int rep = 0; rep < 4; ++rep) {
            int id = rep * 256 + tid;
            int row = id >> 4, c = id & 15;
            *(bf16x8*)&Bs[row * AWK + c * 8] =
                *(const bf16x8*)&WT[(size_t)(n0 + row) * K + k0 + c * 8];
        }
        __syncthreads();
#pragma unroll
        for (int kc = 0; kc < 4; ++kc) {
            bf16x8 a[2], b[2];
#pragma unroll
            for (int i = 0; i < 2; ++i)
                a[i] = *(const bf16x8*)&As[(wm + 16 * i + r16) * AWK + kc * 32 + kb * 8];
#pragma unroll
            for (int j = 0; j < 2; ++j)
                b[j] = *(const bf16x8*)&Bs[(wn + 16 * j + r16) * AWK + kc * 32 + kb * 8];
#pragma unroll
            for (int i = 0; i < 2; ++i)
#pragma unroll
                for (int j = 0; j < 2; ++j)
                    acc[i][j] = __builtin_amdgcn_mfma_f32_16x16x32_bf16(a[i], b[j], acc[i][j], 0, 0, 0);
        }
        __syncthreads();
    }

    const bool toP = (n0 < NP);                 // block-uniform
    ushort* Co = toP ? P : Cs;
    const int Nout = toP ? NP : NS;
    const int nb = toP ? n0 : (n0 - NP);
#pragma unroll
    for (int i = 0; i < 2; ++i) {
#pragma unroll
        for (int j = 0; j < 2; ++j) {
            int cl = wn + 16 * j + r16;
            float bv = bcat[n0 + cl];
#pragma unroll
            for (int r = 0; r < 4; ++r) {
                int row = m0 + wm + 16 * i + kb * 4 + r;
                float v = acc[i][j][r] + bv;
                if (toP) v = fmaxf(v, 0.f);
                Co[(size_t)row * Nout + nb + cl] = f2b(v);
            }
        }
    }
}

// ---------------------------------------------------------------------------
// neigh GEMM, BK=128: C = relu(G @ WnT^T + Cs), 64-wide tiles.
// OUTF: also write f32 Cf (last layer).
// ---------------------------------------------------------------------------
template <int BM, bool OUTF>
__global__ __launch_bounds__(256, 4) void neigh_gemm_k(
    const ushort* __restrict__ G, const ushort* __restrict__ WnT, int K,
    const ushort* __restrict__ Cs, float* __restrict__ Cf,
    ushort* __restrict__ Cb, int N) {
    constexpr int MI = BM / 32;
    __shared__ __align__(16) ushort As[BM * AWK];
    __shared__ __align__(16) ushort Bs[64 * AWK];

    const int tid = threadIdx.x, lane = tid & 63, wave = tid >> 6;
    const int wm = (wave >> 1) * (BM / 2), wn = (wave & 1) * 32;
    const int r16 = lane & 15, kb = lane >> 4;
    const int m0 = blockIdx.y * BM, n0 = blockIdx.x * 64;

    f32x4 acc[MI][2];
#pragma unroll
    for (int i = 0; i < MI; ++i)
#pragma unroll
        for (int j = 0; j < 2; ++j) acc[i][j] = (f32x4)(0.f);

    for (int k0 = 0; k0 < K; k0 += 128) {
#pragma unroll
        for (int rep = 0; rep < BM / 16; ++rep) {
            int id = rep * 256 + tid;
            int row = id >> 4, c = id & 15;
            *(bf16x8*)&As[row * AWK + c * 8] =
                *(const bf16x8*)&G[(size_t)(m0 + row) * K + k0 + c * 8];
        }
#pragma unroll
        for (int rep = 0; rep < 4; ++rep) {
            int id = rep * 256 + tid;
            int row = id >> 4, c = id & 15;
            *(bf16x8*)&Bs[row * AWK + c * 8] =
                *(const bf16x8*)&WnT[(size_t)(n0 + row) * K + k0 + c * 8];
        }
        __syncthreads();
#pragma unroll
        for (int kc = 0; kc < 4; ++kc) {
            bf16x8 a[MI], b[2];
#pragma unroll
            for (int i = 0; i < MI; ++i)
                a[i] = *(const bf16x8*)&As[(wm + 16 * i + r16) * AWK + kc * 32 + kb * 8];
#pragma unroll
            for (int j = 0; j < 2; ++j)
                b[j] = *(const bf16x8*)&Bs[(wn + 16 * j + r16) * AWK + kc * 32 + kb * 8];
#pragma unroll
            for (int i = 0; i < MI; ++i)
#pragma unroll
                for (int j = 0; j < 2; ++j)
                    acc[i][j] = __builtin_amdgcn_mfma_f32_16x16x32_bf16(a[i], b[j], acc[i][j], 0, 0, 0);
        }
        __syncthreads();
    }

#pragma unroll
    for (int i = 0; i < MI; ++i) {
#pragma unroll
        for (int j = 0; j < 2; ++j) {
            int col = n0 + wn + 16 * j + r16;
#pragma unroll
            for (int r = 0; r < 4; ++r) {
                int row = m0 + wm + 16 * i + kb * 4 + r;
                float v = acc[i][j][r] + b2f(Cs[(size_t)row * N + col]);
                v = fmaxf(v, 0.f);
                if constexpr (OUTF) Cf[(size_t)row * N + col] = v;
                Cb[(size_t)row * N + col] = f2b(v);
            }
        }
    }
}

// ---------------------------------------------------------------------------
// segment-max: one wave per node, FPL = DIN/64 features per lane, padded slots.
// ---------------------------------------------------------------------------
template <int DIN>
__global__ __launch_bounds__(256) void seg_k(
    const ushort* __restrict__ Pin, const int* __restrict__ cnt,
    const uint2* __restrict__ slots, ushort* __restrict__ G) {
    constexpr int FPL = DIN / 64;
    const int lane = threadIdx.x & 63, wave = threadIdx.x >> 6;
    int node = blockIdx.x * 4 + wave;
    int f0 = lane * FPL;
    int n = cnt[node]; if (n > CAP) n = CAP;
    const uint2* sl = &slots[(size_t)node * CAP];
    float mx[FPL];
#pragma unroll
    for (int i = 0; i < FPL; ++i) mx[i] = 0.f;
    auto upd = [&](uint s, float w) {
        const uint* hp = (const uint*)&Pin[(size_t)s * DIN + f0];
#pragma unroll
        for (int c = 0; c < FPL / 2; ++c) {
            uint u = hp[c];
            float lo = __uint_as_float(u << 16);
            float hi = __uint_as_float(u & 0xffff0000u);
            mx[2 * c] = fmaxf(mx[2 * c], lo * w);
            mx[2 * c + 1] = fmaxf(mx[2 * c + 1], hi * w);
        }
    };
    int e = 0;
    for (; e + 8 <= n; e += 8) {
        uint2 d[8];
#pragma unroll
        for (int t = 0; t < 8; ++t) d[t] = sl[e + t];
#pragma unroll
        for (int t = 0; t < 8; ++t) upd(d[t].x, __uint_as_float(d[t].y));
    }
    for (; e < n; ++e) { uint2 d = sl[e]; upd(d.x, __uint_as_float(d.y)); }
    uint* gp = (uint*)&G[(size_t)node * DIN + f0];
#pragma unroll
    for (int c = 0; c < FPL / 2; ++c) gp[c] = pack2(mx[2 * c], mx[2 * c + 1]);
}

// ---------------------------------------------------------------------------
// adj = H @ H^T, H [8192][64] bf16, C fp32. 128x128 tile, K=64 single stage.
// Nontemporal stores: adj is write-once, never read.
// ---------------------------------------------------------------------------
__global__ __launch_bounds__(256) void aat_k(const ushort* __restrict__ H,
                                             float* __restrict__ C) {
    __shared__ __align__(16) ushort As[128 * 72];
    __shared__ __align__(16) ushort Bs[128 * 72];
    int tid = threadIdx.x, lane = tid & 63, wave = tid >> 6;
    int wm = (wave >> 1) * 64, wn = (wave & 1) * 64;
    int r16 = lane & 15, kb = lane >> 4;
    int m0 = blockIdx.y * 128, n0 = blockIdx.x * 128;

#pragma unroll
    for (int rep = 0; rep < 4; ++rep) {
        int id = rep * 256 + tid;
        int row = id >> 3, c = id & 7;
        *(bf16x8*)&As[row * 72 + c * 8] = *(const bf16x8*)&H[(size_t)(m0 + row) * 64 + c * 8];
        *(bf16x8*)&Bs[row * 72 + c * 8] = *(const bf16x8*)&H[(size_t)(n0 + row) * 64 + c * 8];
    }
    __syncthreads();

    f32x4 acc[4][4];
#pragma unroll
    for (int i = 0; i < 4; ++i)
#pragma unroll
        for (int j = 0; j < 4; ++j) acc[i][j] = (f32x4)(0.f);

#pragma unroll
    for (int kc = 0; kc < 2; ++kc) {
        bf16x8 a[4], b[4];
#pragma unroll
        for (int i = 0; i < 4; ++i)
            a[i] = *(const bf16x8*)&As[(wm + 16 * i + r16) * 72 + kc * 32 + kb * 8];
#pragma unroll
        for (int j = 0; j < 4; ++j)
            b[j] = *(const bf16x8*)&Bs[(wn + 16 * j + r16) * 72 + kc * 32 + kb * 8];
#pragma unroll
        for (int i = 0; i < 4; ++i)
#pragma unroll
            for (int j = 0; j < 4; ++j)
                acc[i][j] = __builtin_amdgcn_mfma_f32_16x16x32_bf16(a[i], b[j], acc[i][j], 0, 0, 0);
    }

#pragma unroll
    for (int i = 0; i < 4; ++i) {
#pragma unroll
        for (int j = 0; j < 4; ++j) {
            int col = n0 + wn + 16 * j + r16;
#pragma unroll
            for (int r = 0; r < 4; ++r) {
                size_t row = m0 + wm + 16 * i + kb * 4 + r;
                __builtin_nontemporal_store(acc[i][j][r], &C[row * NN + col]);
            }
        }
    }
}

// ---------------------------------------------------------------------------
extern "C" void kernel_launch(void* const* d_in, const int* in_sizes, int n_in,
                              void* d_out, int out_size, void* d_ws, size_t ws_size,
                              hipStream_t stream) {
    const float* feat = (const float*)d_in[0];
    const int* src = (const int*)d_in[1];
    const int* dst = (const int*)d_in[2];
    const float* ew = (const float*)d_in[3];
    const float* Wp1 = (const float*)d_in[5];
    const float* bp1 = (const float*)d_in[6];
    const float* Ws1 = (const float*)d_in[7];
    const float* Wn1 = (const float*)d_in[8];
    const float* b1  = (const float*)d_in[9];
    const float* Wp2 = (const float*)d_in[10];
    const float* bp2 = (const float*)d_in[11];
    const float* Ws2 = (const float*)d_in[12];
    const float* Wn2 = (const float*)d_in[13];
    const float* b2  = (const float*)d_in[14];
    const float* Wp3 = (const float*)d_in[15];
    const float* bp3 = (const float*)d_in[16];
    const float* Ws3 = (const float*)d_in[17];
    const float* Wn3 = (const float*)d_in[18];
    const float* b3  = (const float*)d_in[19];

    float* out = (float*)d_out;          // hd fp32 [8192][64]
    float* adj = out + (size_t)NN * 64;  // adj fp32 [8192][8192]

    char* ws = (char*)d_ws;
    int* cnt      = (int*)(ws + 0x0);          // 32 KB
    uint2* slots  = (uint2*)(ws + 0x10000);    // 6 MB
    ushort* WpsT1 = (ushort*)(ws + 0x620000);  // [384][128] 96 KB
    ushort* WpsT2 = (ushort*)(ws + 0x638000);  // [512][256] 256 KB
    ushort* WpsT3 = (ushort*)(ws + 0x678000);  // [320][256] 160 KB
    ushort* WnT1  = (ushort*)(ws + 0x6A0000);  // [256][128] 64 KB
    ushort* WnT2  = (ushort*)(ws + 0x6B0000);  // [256][256] 128 KB
    ushort* WnT3  = (ushort*)(ws + 0x6D0000);  // [64][256]  32 KB
    float* bcat1  = (float*)(ws + 0x6D8000);   // 384
    float* bcat2  = (float*)(ws + 0x6D9000);   // 512
    float* bcat3  = (float*)(ws + 0x6DB000);   // 320
    ushort* P  = (ushort*)(ws + 0x700000);     // pool bf16 [N][<=256]
    ushort* G  = (ushort*)(ws + 0xB00000);     // agg bf16 [N][<=256]
    ushort* X  = (ushort*)(ws + 0xF00000);     // x2 bf16 [N][256]
    ushort* Y  = (ushort*)(ws + 0x1300000);    // x3 bf16 [N][256]
    ushort* Cs = (ushort*)(ws + 0x1700000);    // self bf16 [N][<=256]
    ushort* hdb = (ushort*)(ws + 0x1B00000);   // hd bf16 [N][64]

    hipMemsetAsync(cnt, 0, NN * sizeof(int), stream);

    // prep: scatter || weight transposes (into concat buffers) || bias concat
    PrepArgs pa;
    pa.src = src; pa.dst = dst; pa.ew = ew; pa.cnt = cnt; pa.slots = slots;
    const float* wsrc[9] = {Wp1, Ws1, Wn1, Wp2, Ws2, Wn2, Wp3, Ws3, Wn3};
    ushort* wdst[9] = {WpsT1, WpsT1 + 128 * 128, WnT1,
                       WpsT2, WpsT2 + 256 * 256, WnT2,
                       WpsT3, WpsT3 + 256 * 256, WnT3};
    for (int i = 0; i < 9; ++i) { pa.w[i] = wsrc[i]; pa.wt[i] = wdst[i]; }
    pa.bp1 = bp1; pa.b1 = b1; pa.bp2 = bp2; pa.b2 = b2; pa.bp3 = bp3; pa.b3 = b3;
    pa.bcat1 = bcat1; pa.bcat2 = bcat2; pa.bcat3 = bcat3;
    prep_scatter_k<<<2497, 256, 0, stream>>>(pa);

    // layer 1 (128 -> 256): pool+self fused (N=384), then seg, then neigh
    ps_gemm_k<128, 256, true><<<dim3(6, 128), 256, 0, stream>>>(
        feat, WpsT1, 128, bcat1, P, Cs);
    seg_k<128><<<NN / 4, 256, 0, stream>>>(P, cnt, slots, G);
    neigh_gemm_k<64, false><<<dim3(4, 128), 256, 0, stream>>>(
        G, WnT1, 128, Cs, nullptr, X, 256);

    // layer 2 (256 -> 256)
    ps_gemm_k<256, 256, false><<<dim3(8, 128), 256, 0, stream>>>(
        X, WpsT2, 256, bcat2, P, Cs);
    seg_k<256><<<NN / 4, 256, 0, stream>>>(P, cnt, slots, G);
    neigh_gemm_k<64, false><<<dim3(4, 128), 256, 0, stream>>>(
        G, WnT2, 256, Cs, nullptr, Y, 256);

    // layer 3 (256 -> 64)
    ps_gemm_k<256, 64, false><<<dim3(5, 128), 256, 0, stream>>>(
        Y, WpsT3, 256, bcat3, P, Cs);
    seg_k<256><<<NN / 4, 256, 0, stream>>>(P, cnt, slots, G);
    neigh_gemm_k<32, true><<<dim3(1, 256), 256, 0, stream>>>(
        G, WnT3, 256, Cs, out, hdb, 64);

    // adj = hd @ hd^T
    aat_k<<<dim3(NN / 128, NN / 128), 256, 0, stream>>>(hdb, adj);
}

// Round 11
// 162.895 us; speedup vs baseline: 7.3508x; 1.1487x over previous
//
#include <hip/hip_runtime.h>
#include <hip/hip_bf16.h>

#define NN 8192
#define NE 262144
#define CAP 96
#define AWK 136   // 128 + 8 pad (ushorts)

typedef __attribute__((ext_vector_type(8))) __bf16 bf16x8;
typedef __attribute__((ext_vector_type(4))) float f32x4;

__device__ __forceinline__ ushort f2b(float v) {
    __hip_bfloat16 b = __float2bfloat16(v);
    return *reinterpret_cast<ushort*>(&b);
}
__device__ __forceinline__ uint pack2(float lo, float hi) {
    return (uint)f2b(lo) | ((uint)f2b(hi) << 16);
}
__device__ __forceinline__ float b2f(ushort u) {
    return __uint_as_float(((uint)u) << 16);
}

// ---------------------------------------------------------------------------
// 64x64 GEMM tile, BK=128 (verified in R9): C[by,bx] = act(A @ BT^T + addend)
// A [8192][K] (f32 converted on the fly if A1F32, else bf16), BT [N][K] bf16.
// 4 waves (2x2), wave tile 32x32. OUTMODE: 0=bf16, 1=f32, 2=both.
// ADDC: addend = bf16 cin[row][col]; else bias[col].
// ---------------------------------------------------------------------------
template <bool A1F32, bool RELU, int OUTMODE, bool ADDC>
__device__ __forceinline__ void gemm_tile64(
    int by, int bx, const void* __restrict__ Av, const ushort* __restrict__ BT,
    int K, const float* __restrict__ bias, const ushort* __restrict__ cin,
    float* __restrict__ Cf, ushort* __restrict__ Cb, int N,
    ushort* As, ushort* Bs) {
    const int tid = threadIdx.x, lane = tid & 63, wave = tid >> 6;
    const int wm = (wave >> 1) * 32, wn = (wave & 1) * 32;
    const int r16 = lane & 15, kb = lane >> 4;
    const int m0 = by * 64, n0 = bx * 64;

    f32x4 acc[2][2];
#pragma unroll
    for (int i = 0; i < 2; ++i)
#pragma unroll
        for (int j = 0; j < 2; ++j) acc[i][j] = (f32x4)(0.f);

    for (int k0 = 0; k0 < K; k0 += 128) {
        if constexpr (A1F32) {
            const float* A = (const float*)Av;
#pragma unroll
            for (int rep = 0; rep < 8; ++rep) {
                int id = rep * 256 + tid;
                int row = id >> 5, c = id & 31;
                float4 f = *(const float4*)&A[(size_t)(m0 + row) * K + k0 + c * 4];
                uint2 o; o.x = pack2(f.x, f.y); o.y = pack2(f.z, f.w);
                *(uint2*)&As[row * AWK + c * 4] = o;
            }
        } else {
            const ushort* A = (const ushort*)Av;
#pragma unroll
            for (int rep = 0; rep < 4; ++rep) {
                int id = rep * 256 + tid;
                int row = id >> 4, c = id & 15;
                *(bf16x8*)&As[row * AWK + c * 8] =
                    *(const bf16x8*)&A[(size_t)(m0 + row) * K + k0 + c * 8];
            }
        }
#pragma unroll
        for (int rep = 0; rep < 4; ++rep) {
            int id = rep * 256 + tid;
            int row = id >> 4, c = id & 15;
            *(bf16x8*)&Bs[row * AWK + c * 8] =
                *(const bf16x8*)&BT[(size_t)(n0 + row) * K + k0 + c * 8];
        }
        __syncthreads();
#pragma unroll
        for (int kc = 0; kc < 4; ++kc) {
            bf16x8 a[2], b[2];
#pragma unroll
            for (int i = 0; i < 2; ++i)
                a[i] = *(const bf16x8*)&As[(wm + 16 * i + r16) * AWK + kc * 32 + kb * 8];
#pragma unroll
            for (int j = 0; j < 2; ++j)
                b[j] = *(const bf16x8*)&Bs[(wn + 16 * j + r16) * AWK + kc * 32 + kb * 8];
#pragma unroll
            for (int i = 0; i < 2; ++i)
#pragma unroll
                for (int j = 0; j < 2; ++j)
                    acc[i][j] = __builtin_amdgcn_mfma_f32_16x16x32_bf16(a[i], b[j], acc[i][j], 0, 0, 0);
        }
        __syncthreads();
    }

#pragma unroll
    for (int i = 0; i < 2; ++i) {
#pragma unroll
        for (int j = 0; j < 2; ++j) {
            int col = n0 + wn + 16 * j + r16;
            float bv = ADDC ? 0.f : bias[col];
#pragma unroll
            for (int r = 0; r < 4; ++r) {
                int row = m0 + wm + 16 * i + kb * 4 + r;
                float v = acc[i][j][r];
                if constexpr (ADDC) v += b2f(cin[(size_t)row * N + col]);
                else v += bv;
                if (RELU) v = fmaxf(v, 0.f);
                if (OUTMODE != 0) Cf[(size_t)row * N + col] = v;
                if (OUTMODE != 1) Cb[(size_t)row * N + col] = f2b(v);
            }
        }
    }
}

// ---------------------------------------------------------------------------
// segmax for 4 nodes (1 wave each), verified in R9.
// ---------------------------------------------------------------------------
template <int DIN>
__device__ __forceinline__ void seg4(
    int grp, const ushort* __restrict__ Pin, const int* __restrict__ cnt,
    const uint2* __restrict__ slots, ushort* __restrict__ G) {
    constexpr int FPL = DIN / 64;
    const int lane = threadIdx.x & 63, wave = threadIdx.x >> 6;
    int node = grp * 4 + wave;
    int f0 = lane * FPL;
    int n = cnt[node]; if (n > CAP) n = CAP;
    const uint2* sl = &slots[(size_t)node * CAP];
    float mx[FPL];
#pragma unroll
    for (int i = 0; i < FPL; ++i) mx[i] = 0.f;
    auto upd = [&](uint s, float w) {
        const uint* hp = (const uint*)&Pin[(size_t)s * DIN + f0];
#pragma unroll
        for (int c = 0; c < FPL / 2; ++c) {
            uint u = hp[c];
            float lo = __uint_as_float(u << 16);
            float hi = __uint_as_float(u & 0xffff0000u);
            mx[2 * c] = fmaxf(mx[2 * c], lo * w);
            mx[2 * c + 1] = fmaxf(mx[2 * c + 1], hi * w);
        }
    };
    int e = 0;
    for (; e + 8 <= n; e += 8) {
        uint2 d[8];
#pragma unroll
        for (int t = 0; t < 8; ++t) d[t] = sl[e + t];
#pragma unroll
        for (int t = 0; t < 8; ++t) upd(d[t].x, __uint_as_float(d[t].y));
    }
    for (; e < n; ++e) { uint2 d = sl[e]; upd(d.x, __uint_as_float(d.y)); }
    uint* gp = (uint*)&G[(size_t)node * DIN + f0];
#pragma unroll
    for (int c = 0; c < FPL / 2; ++c) gp[c] = pack2(mx[2 * c], mx[2 * c + 1]);
}

// ---------------------------------------------------------------------------
// prep: zero cnt (blocks 0..31) + 9 weight transposes ([K][N] f32 -> [N][K] bf16)
// ---------------------------------------------------------------------------
struct PrepArgs {
    int* cnt;
    const float* w[9]; ushort* wt[9];
};

__global__ __launch_bounds__(256) void prep_k(PrepArgs a) {
    const int bid = blockIdx.x, tid = threadIdx.x;
    if (bid < 32) { a.cnt[bid * 256 + tid] = 0; return; }
    int id = (bid - 32) * 256 + tid;     // 376832 total
    if (id >= 376832) return;
    const int cum[10] = {0, 16384, 49152, 81920, 147456, 212992, 278528, 344064, 360448, 376832};
    const int KK[9] = {128, 128, 128, 256, 256, 256, 256, 256, 256};
    const int LN[9] = {7, 8, 8, 8, 8, 8, 8, 6, 6};   // log2(N)
    int m = 0;
#pragma unroll
    for (int t = 1; t < 9; ++t) m += (id >= cum[t]);
    int local = id - cum[m];
    int K = KK[m], ln = LN[m];
    int k = local >> ln, n = local & ((1 << ln) - 1);
    a.wt[m][n * K + k] = f2b(a.w[m][local]);
}

// ---------------------------------------------------------------------------
// scatter || pool1, INTERLEAVED (bid%5==4 -> pool1 tile, else scatter chunk).
// pool1: P = relu(feat @ Wp1^T + bp1), tiles (by,bx) over [8192]x[128].
// ---------------------------------------------------------------------------
__global__ __launch_bounds__(256, 4) void scat_pool1_k(
    const int* __restrict__ src, const int* __restrict__ dst,
    const float* __restrict__ ew, int* __restrict__ cnt, uint2* __restrict__ slots,
    const float* __restrict__ feat, const ushort* __restrict__ WpT,
    const float* __restrict__ bp, ushort* __restrict__ P) {
    __shared__ __align__(16) ushort As[64 * AWK];
    __shared__ __align__(16) ushort Bs[64 * AWK];
    const int g = blockIdx.x / 5, r = blockIdx.x % 5;
    if (r == 4) {   // pool1 tile g = 0..255
        gemm_tile64<true, true, 0, false>(g >> 1, g & 1, feat, WpT, 128,
                                          bp, nullptr, nullptr, P, 128, As, Bs);
    } else {        // scatter chunk g*4+r = 0..1023
        int e = (g * 4 + r) * 256 + threadIdx.x;
        int d = dst[e];
        int p = atomicAdd(&cnt[d], 1);
        if (p < CAP) slots[(size_t)d * CAP + p] = make_uint2((uint)src[e], __float_as_uint(ew[e]));
    }
}

// ---------------------------------------------------------------------------
// seg || self, INTERLEAVED: bid%(RATIO+1)==RATIO -> self tile, else seg group.
// self: Cs = A @ WsT^T + bias (bf16, no relu).
// ---------------------------------------------------------------------------
template <int DIN, int RATIO, bool A1F32, int KSELF, int NSELF>
__global__ __launch_bounds__(256, 4) void seg_self_k(
    const ushort* __restrict__ Pin, const int* __restrict__ cnt,
    const uint2* __restrict__ slots, ushort* __restrict__ G,
    const void* __restrict__ Av, const ushort* __restrict__ WsT,
    const float* __restrict__ bias, ushort* __restrict__ Cs) {
    __shared__ __align__(16) ushort As[64 * AWK];
    __shared__ __align__(16) ushort Bs[64 * AWK];
    const int g = blockIdx.x / (RATIO + 1), r = blockIdx.x % (RATIO + 1);
    if (r == RATIO) {   // self tile g
        constexpr int NBX = NSELF / 64;
        gemm_tile64<A1F32, false, 0, false>(g / NBX, g % NBX, Av, WsT, KSELF,
                                            bias, nullptr, nullptr, Cs, NSELF, As, Bs);
    } else {
        seg4<DIN>(g * RATIO + r, Pin, cnt, slots, G);
    }
}

// ---------------------------------------------------------------------------
// plain GEMM wrappers
// ---------------------------------------------------------------------------
template <bool A1F32, bool RELU, int OUTMODE, bool ADDC>
__global__ __launch_bounds__(256, 4) void gemm_k(
    const void* __restrict__ Av, const ushort* __restrict__ BT, int K,
    const float* __restrict__ bias, const ushort* __restrict__ cin,
    float* __restrict__ Cf, ushort* __restrict__ Cb, int N) {
    __shared__ __align__(16) ushort As[64 * AWK];
    __shared__ __align__(16) ushort Bs[64 * AWK];
    gemm_tile64<A1F32, RELU, OUTMODE, ADDC>(blockIdx.y, blockIdx.x, Av, BT, K,
                                            bias, cin, Cf, Cb, N, As, Bs);
}

// ---------------------------------------------------------------------------
// adj = H @ H^T, H [8192][64] bf16, C fp32. 128x128 tile, K=64 single stage.
// ---------------------------------------------------------------------------
__global__ __launch_bounds__(256) void aat_k(const ushort* __restrict__ H,
                                             float* __restrict__ C) {
    __shared__ __align__(16) ushort As[128 * 72];
    __shared__ __align__(16) ushort Bs[128 * 72];
    int tid = threadIdx.x, lane = tid & 63, wave = tid >> 6;
    int wm = (wave >> 1) * 64, wn = (wave & 1) * 64;
    int r16 = lane & 15, kb = lane >> 4;
    int m0 = blockIdx.y * 128, n0 = blockIdx.x * 128;

#pragma unroll
    for (int rep = 0; rep < 4; ++rep) {
        int id = rep * 256 + tid;
        int row = id >> 3, c = id & 7;
        *(bf16x8*)&As[row * 72 + c * 8] = *(const bf16x8*)&H[(size_t)(m0 + row) * 64 + c * 8];
        *(bf16x8*)&Bs[row * 72 + c * 8] = *(const bf16x8*)&H[(size_t)(n0 + row) * 64 + c * 8];
    }
    __syncthreads();

    f32x4 acc[4][4];
#pragma unroll
    for (int i = 0; i < 4; ++i)
#pragma unroll
        for (int j = 0; j < 4; ++j) acc[i][j] = (f32x4)(0.f);

#pragma unroll
    for (int kc = 0; kc < 2; ++kc) {
        bf16x8 a[4], b[4];
#pragma unroll
        for (int i = 0; i < 4; ++i)
            a[i] = *(const bf16x8*)&As[(wm + 16 * i + r16) * 72 + kc * 32 + kb * 8];
#pragma unroll
        for (int j = 0; j < 4; ++j)
            b[j] = *(const bf16x8*)&Bs[(wn + 16 * j + r16) * 72 + kc * 32 + kb * 8];
#pragma unroll
        for (int i = 0; i < 4; ++i)
#pragma unroll
            for (int j = 0; j < 4; ++j)
                acc[i][j] = __builtin_amdgcn_mfma_f32_16x16x32_bf16(a[i], b[j], acc[i][j], 0, 0, 0);
    }

#pragma unroll
    for (int i = 0; i < 4; ++i) {
#pragma unroll
        for (int j = 0; j < 4; ++j) {
            int col = n0 + wn + 16 * j + r16;
#pragma unroll
            for (int r = 0; r < 4; ++r) {
                size_t row = m0 + wm + 16 * i + kb * 4 + r;
                C[row * NN + col] = acc[i][j][r];
            }
        }
    }
}

// ---------------------------------------------------------------------------
extern "C" void kernel_launch(void* const* d_in, const int* in_sizes, int n_in,
                              void* d_out, int out_size, void* d_ws, size_t ws_size,
                              hipStream_t stream) {
    const float* feat = (const float*)d_in[0];
    const int* src = (const int*)d_in[1];
    const int* dst = (const int*)d_in[2];
    const float* ew = (const float*)d_in[3];
    const float* Wp1 = (const float*)d_in[5];
    const float* bp1 = (const float*)d_in[6];
    const float* Ws1 = (const float*)d_in[7];
    const float* Wn1 = (const float*)d_in[8];
    const float* b1  = (const float*)d_in[9];
    const float* Wp2 = (const float*)d_in[10];
    const float* bp2 = (const float*)d_in[11];
    const float* Ws2 = (const float*)d_in[12];
    const float* Wn2 = (const float*)d_in[13];
    const float* b2  = (const float*)d_in[14];
    const float* Wp3 = (const float*)d_in[15];
    const float* bp3 = (const float*)d_in[16];
    const float* Ws3 = (const float*)d_in[17];
    const float* Wn3 = (const float*)d_in[18];
    const float* b3  = (const float*)d_in[19];

    float* out = (float*)d_out;          // hd fp32 [8192][64]
    float* adj = out + (size_t)NN * 64;  // adj fp32 [8192][8192]

    char* ws = (char*)d_ws;
    int* cnt      = (int*)(ws + 0x0);          // 32 KB
    uint2* slots  = (uint2*)(ws + 0x10000);    // 6 MB
    ushort* Wp1T = (ushort*)(ws + 0x620000);
    ushort* Ws1T = (ushort*)(ws + 0x628000);
    ushort* Wn1T = (ushort*)(ws + 0x638000);
    ushort* Wp2T = (ushort*)(ws + 0x648000);
    ushort* Ws2T = (ushort*)(ws + 0x668000);
    ushort* Wn2T = (ushort*)(ws + 0x688000);
    ushort* Wp3T = (ushort*)(ws + 0x6A8000);
    ushort* Ws3T = (ushort*)(ws + 0x6C8000);
    ushort* Wn3T = (ushort*)(ws + 0x6D0000);
    ushort* P  = (ushort*)(ws + 0x700000);     // pool bf16 [N][<=256]
    ushort* G  = (ushort*)(ws + 0xB00000);     // agg bf16 [N][<=256]
    ushort* X  = (ushort*)(ws + 0xF00000);     // x2 bf16 [N][256]
    ushort* Y  = (ushort*)(ws + 0x1300000);    // x3 bf16 [N][256]
    ushort* Cs = (ushort*)(ws + 0x1700000);    // self bf16 [N][<=256]
    ushort* hdb = (ushort*)(ws + 0x1B00000);   // hd bf16 [N][64]

    // 1) prep: zero cnt + weight transposes
    PrepArgs pa;
    pa.cnt = cnt;
    const float* wsrc[9] = {Wp1, Ws1, Wn1, Wp2, Ws2, Wn2, Wp3, Ws3, Wn3};
    ushort* wdst[9] = {Wp1T, Ws1T, Wn1T, Wp2T, Ws2T, Wn2T, Wp3T, Ws3T, Wn3T};
    for (int i = 0; i < 9; ++i) { pa.w[i] = wsrc[i]; pa.wt[i] = wdst[i]; }
    prep_k<<<32 + 1472, 256, 0, stream>>>(pa);

    // 2) scatter || pool1 (interleaved)
    scat_pool1_k<<<1280, 256, 0, stream>>>(src, dst, ew, cnt, slots, feat, Wp1T, bp1, P);

    // layer 1 (128 -> 256)
    seg_self_k<128, 4, true, 128, 256><<<2560, 256, 0, stream>>>(
        P, cnt, slots, G, feat, Ws1T, b1, Cs);
    gemm_k<false, true, 0, true><<<dim3(4, 128), 256, 0, stream>>>(
        G, Wn1T, 128, nullptr, Cs, nullptr, X, 256);                  // X = relu(G@Wn1 + Cs)

    // layer 2 (256 -> 256)
    gemm_k<false, true, 0, false><<<dim3(4, 128), 256, 0, stream>>>(
        X, Wp2T, 256, bp2, nullptr, nullptr, P, 256);                 // pool2
    seg_self_k<256, 4, false, 256, 256><<<2560, 256, 0, stream>>>(
        P, cnt, slots, G, X, Ws2T, b2, Cs);
    gemm_k<false, true, 0, true><<<dim3(4, 128), 256, 0, stream>>>(
        G, Wn2T, 256, nullptr, Cs, nullptr, Y, 256);                  // Y

    // layer 3 (256 -> 64)
    gemm_k<false, true, 0, false><<<dim3(4, 128), 256, 0, stream>>>(
        Y, Wp3T, 256, bp3, nullptr, nullptr, P, 256);                 // pool3
    seg_self_k<256, 16, false, 256, 64><<<2176, 256, 0, stream>>>(
        P, cnt, slots, G, Y, Ws3T, b3, Cs);
    gemm_k<false, true, 2, true><<<dim3(1, 128), 256, 0, stream>>>(
        G, Wn3T, 256, nullptr, Cs, out, hdb, 64);                     // hd fp32 + bf16

    // adj = hd @ hd^T
    aat_k<<<dim3(NN / 128, NN / 128), 256, 0, stream>>>(hdb, adj);
}